// Round 1
// baseline (9.868 us; speedup 1.0000x reference)
//
#include <hip/hip_runtime.h>

#define NQ 14

// ---- compile-time composition of the 28 CNOT permutations (GF(2)-linear) ----
constexpr unsigned perm_step(int k, unsigned v) {
    const int step = (k < NQ) ? 1 : 2;
    const int c = k % NQ;
    const int t = (c + step) % NQ;
    const unsigned cm = 1u << (NQ - 1 - c);
    const unsigned tm = 1u << (NQ - 1 - t);
    return (v & cm) ? (v ^ tm) : v;
}

// Q(i) = perm_0(perm_1(...perm_27(i))): final[i] = prod_state[Q(i)]
constexpr unsigned Qapply(unsigned v) {
    for (int k = 2 * NQ - 1; k >= 0; --k) v = perm_step(k, v);
    return v;
}
constexpr unsigned Qinvapply(unsigned v) {
    for (int k = 0; k < 2 * NQ; ++k) v = perm_step(k, v);
    return v;
}

struct MaskTab {
    unsigned f[NQ];   // flip pattern Q(e_w)       (bits over integer positions p)
    unsigned m[NQ];   // parity mask: row w of Q^-1
    float    sg[NQ];  // (-1)^((k-1)/2), k = popcount(f & m) (always odd)
};

constexpr MaskTab make_masks() {
    MaskTab T{};
    for (int w = 0; w < NQ; ++w) {
        T.f[w] = Qapply(1u << (NQ - 1 - w));
        unsigned mm = 0;
        for (int p = 0; p < NQ; ++p) {
            const unsigned qi = Qinvapply(1u << p);
            if ((qi >> (NQ - 1 - w)) & 1u) mm |= (1u << p);
        }
        T.m[w] = mm;
        unsigned kk = 0;
        const unsigned fm = T.f[w] & mm;
        for (int p = 0; p < NQ; ++p) kk += (fm >> p) & 1u;
        T.sg[w] = (((kk - 1u) / 2u) & 1u) ? -1.0f : 1.0f;
    }
    return T;
}

constexpr MaskTab TAB = make_masks();

// One thread per batch element. Closed-form expectation per output qubit.
__global__ __launch_bounds__(64)
void qulinear_expect_kernel(const float* __restrict__ x,
                            const float* __restrict__ u3,
                            float* __restrict__ out, int B)
{
    __shared__ float cth[NQ], scl[NQ], ssl[NQ];
    if (threadIdx.x < NQ) {
        const int w = threadIdx.x;
        const float th  = u3[3 * w + 0];
        const float lam = u3[3 * w + 2];   // phi (u3[3w+1]) cancels in U3^dag Z U3
        float st, ct, sl, cl;
        sincosf(th, &st, &ct);
        sincosf(lam, &sl, &cl);
        cth[w] = ct;
        scl[w] = st * cl;
        ssl[w] = st * sl;
    }
    __syncthreads();

    const int b = blockIdx.x * blockDim.x + threadIdx.x;
    if (b >= B) return;

    // per-qubit scalars from the product state q = RZ(rz) RY(ry) H |0>
    float z[NQ], t[NQ], g[NQ];
#pragma unroll
    for (int v = 0; v < NQ; ++v) {
        const float xv = x[b * NQ + v];
        const float x2 = xv * xv;
        const float cy = rsqrtf(1.0f + x2);        // cos(atan(x))
        const float cz = rsqrtf(1.0f + x2 * x2);   // cos(atan(x^2))
        z[v] = -xv * cy;                           // -sin(ry)
        t[v] = cy * cz;                            // cos(ry)cos(rz)
        g[v] = x2 * cy * cz;                       // cos(ry)sin(rz)
    }

#pragma unroll
    for (int w = 0; w < NQ; ++w) {
        const unsigned fm = TAB.f[w];
        const unsigned mm = TAB.m[w];
        float P1 = 1.0f, P2 = 1.0f, P3 = 1.0f;
#pragma unroll
        for (int p = 0; p < NQ; ++p) {
            const int v = NQ - 1 - p;               // qubit index for bit position p
            const bool inF = (fm >> p) & 1u;
            const bool inM = (mm >> p) & 1u;
            if (inM)            P1 *= z[v];
            if (inF)            P2 *= t[v];
            if (inF && inM)     P3 *= g[v];
            else if (inF)       P3 *= t[v];
            else if (inM)       P3 *= z[v];
        }
        out[b * NQ + w] = cth[w] * P1 - scl[w] * P2 + TAB.sg[w] * ssl[w] * P3;
    }
}

extern "C" void kernel_launch(void* const* d_in, const int* in_sizes, int n_in,
                              void* d_out, int out_size, void* d_ws, size_t ws_size,
                              hipStream_t stream) {
    const float* x  = (const float*)d_in[0];   // [B, 14] f32
    const float* u3 = (const float*)d_in[1];   // [14, 3] f32
    float* out = (float*)d_out;                // [B, 14] f32
    const int B = in_sizes[0] / NQ;
    const int block = 64;
    const int grid = (B + block - 1) / block;
    qulinear_expect_kernel<<<grid, block, 0, stream>>>(x, u3, out, B);
}

// Round 2
// 9.753 us; speedup vs baseline: 1.0118x; 1.0118x over previous
//
#include <hip/hip_runtime.h>

#define NQ 14
#define BLK 128
#define PAD 15   // 14 -> 15 leading dim: per-row LDS reads become conflict-free

// ---- compile-time composition of the 28 CNOT permutations (GF(2)-linear) ----
constexpr unsigned perm_step(int k, unsigned v) {
    const int step = (k < NQ) ? 1 : 2;
    const int c = k % NQ;
    const int t = (c + step) % NQ;
    const unsigned cm = 1u << (NQ - 1 - c);
    const unsigned tm = 1u << (NQ - 1 - t);
    return (v & cm) ? (v ^ tm) : v;
}

constexpr unsigned Qapply(unsigned v) {
    for (int k = 2 * NQ - 1; k >= 0; --k) v = perm_step(k, v);
    return v;
}
constexpr unsigned Qinvapply(unsigned v) {
    for (int k = 0; k < 2 * NQ; ++k) v = perm_step(k, v);
    return v;
}

struct MaskTab {
    unsigned f[NQ];
    unsigned m[NQ];
    float    sg[NQ];
};

constexpr MaskTab make_masks() {
    MaskTab T{};
    for (int w = 0; w < NQ; ++w) {
        T.f[w] = Qapply(1u << (NQ - 1 - w));
        unsigned mm = 0;
        for (int p = 0; p < NQ; ++p) {
            const unsigned qi = Qinvapply(1u << p);
            if ((qi >> (NQ - 1 - w)) & 1u) mm |= (1u << p);
        }
        T.m[w] = mm;
        unsigned kk = 0;
        const unsigned fm = T.f[w] & mm;
        for (int p = 0; p < NQ; ++p) kk += (fm >> p) & 1u;
        T.sg[w] = (((kk - 1u) / 2u) & 1u) ? -1.0f : 1.0f;
    }
    return T;
}

constexpr MaskTab TAB = make_masks();

__global__ __launch_bounds__(BLK)
void qulinear_expect_kernel(const float* __restrict__ x,
                            const float* __restrict__ u3,
                            float* __restrict__ out, int B)
{
    __shared__ float lds[BLK * PAD];
    __shared__ float cth[NQ], scl[NQ], ssl[NQ];

    const int total = B * NQ;
    const int base_e = blockIdx.x * (BLK * NQ);   // first flat element of this block

    if (threadIdx.x < NQ) {
        const int w = threadIdx.x;
        const float th  = u3[3 * w + 0];
        const float lam = u3[3 * w + 2];          // phi cancels in U3^dag Z U3
        float st, ct, sl, cl;
        sincosf(th, &st, &ct);
        sincosf(lam, &sl, &cl);
        cth[w] = ct;
        scl[w] = st * cl;
        ssl[w] = st * sl;
    }

    // ---- coalesced float4 load of x, scattered into padded LDS rows ----
    for (int i = threadIdx.x; i < (BLK * NQ) / 4; i += BLK) {
        const int e = i * 4;
        float4 v4 = make_float4(0.f, 0.f, 0.f, 0.f);
        if (base_e + e + 3 < total)
            v4 = *(const float4*)(x + base_e + e);
#pragma unroll
        for (int j = 0; j < 4; ++j) {
            const int ee = e + j;
            lds[(ee / NQ) * PAD + (ee % NQ)] = (&v4.x)[j];
        }
    }
    __syncthreads();

    // ---- per-qubit scalars from the product state q = RZ RY H |0> ----
    const int r = threadIdx.x;
    float z[NQ], t[NQ], g[NQ];
#pragma unroll
    for (int v = 0; v < NQ; ++v) {
        const float xv = lds[r * PAD + v];
        const float x2 = xv * xv;
        const float cy = rsqrtf(1.0f + x2);
        const float cz = rsqrtf(1.0f + x2 * x2);
        z[v] = -xv * cy;
        t[v] = cy * cz;
        g[v] = x2 * cy * cz;
    }

    float outv[NQ];
#pragma unroll
    for (int w = 0; w < NQ; ++w) {
        const unsigned fm = TAB.f[w];
        const unsigned mm = TAB.m[w];
        // two alternating partials per product: halves the dependent mult chain
        float P1a = 1.f, P1b = 1.f, P2a = 1.f, P2b = 1.f, P3a = 1.f, P3b = 1.f;
#pragma unroll
        for (int p = 0; p < NQ; ++p) {
            const int v = NQ - 1 - p;
            const bool inF = (fm >> p) & 1u;
            const bool inM = (mm >> p) & 1u;
            const bool alt = p & 1;
            if (inM)          { if (alt) P1b *= z[v]; else P1a *= z[v]; }
            if (inF)          { if (alt) P2b *= t[v]; else P2a *= t[v]; }
            if (inF && inM)   { if (alt) P3b *= g[v]; else P3a *= g[v]; }
            else if (inF)     { if (alt) P3b *= t[v]; else P3a *= t[v]; }
            else if (inM)     { if (alt) P3b *= z[v]; else P3a *= z[v]; }
        }
        outv[w] = cth[w] * (P1a * P1b) - scl[w] * (P2a * P2b)
                + TAB.sg[w] * ssl[w] * (P3a * P3b);
    }
    __syncthreads();   // LDS reuse: all x reads done before overwrite

    // ---- padded LDS -> coalesced float4 store ----
#pragma unroll
    for (int w = 0; w < NQ; ++w) lds[r * PAD + w] = outv[w];
    __syncthreads();

    for (int i = threadIdx.x; i < (BLK * NQ) / 4; i += BLK) {
        const int e = i * 4;
        if (base_e + e + 3 < total) {
            float4 v4;
#pragma unroll
            for (int j = 0; j < 4; ++j) {
                const int ee = e + j;
                (&v4.x)[j] = lds[(ee / NQ) * PAD + (ee % NQ)];
            }
            *(float4*)(out + base_e + e) = v4;
        }
    }
}

extern "C" void kernel_launch(void* const* d_in, const int* in_sizes, int n_in,
                              void* d_out, int out_size, void* d_ws, size_t ws_size,
                              hipStream_t stream) {
    const float* x  = (const float*)d_in[0];   // [B, 14] f32
    const float* u3 = (const float*)d_in[1];   // [14, 3] f32
    float* out = (float*)d_out;                // [B, 14] f32
    const int B = in_sizes[0] / NQ;
    const int grid = (B + BLK - 1) / BLK;      // B=2048 -> 16 blocks x 128
    qulinear_expect_kernel<<<grid, BLK, 0, stream>>>(x, u3, out, B);
}